// Round 12
// baseline (196.977 us; speedup 1.0000x reference)
//
#include <hip/hip_runtime.h>
#include <hip/hip_bf16.h>
#include <stdint.h>

typedef unsigned short u16;
typedef __attribute__((ext_vector_type(8))) short bf16x8;   // 8 bf16 in 4 VGPRs
typedef __attribute__((ext_vector_type(4))) float f32x4;

__device__ __forceinline__ u16 f2bf(float f) {
    union { float f; unsigned int i; } c; c.f = f;
    unsigned int x = c.i;
    return (u16)((x + 0x7FFFu + ((x >> 16) & 1u)) >> 16);   // RNE
}
__device__ __forceinline__ u16 f2bf_fast(float f) {         // tie-away, 2 VALU
    union { float f; unsigned int i; } c; c.f = f;
    return (u16)((c.i + 0x8000u) >> 16);
}

// async global->LDS, 16B per lane; LDS dst = uniform base + lane*16
__device__ __forceinline__ void glds16(const u16* g, u16* l) {
    __builtin_amdgcn_global_load_lds(
        (const __attribute__((address_space(1))) void*)g,
        (__attribute__((address_space(3))) void*)l, 16, 0, 0);
}

// manual sync: raw barrier + partial vmcnt waits. LESSON (r13/r14): only
// glds staging (vmcnt-tracked) may publish LDS across waves with these;
// cross-wave ds_write publication raced even with lgkmcnt(0) — banned.
__device__ __forceinline__ void bar() { asm volatile("s_barrier" ::: "memory"); }
template <int N> __device__ __forceinline__ void waitv() {
    if constexpr (N == 0)      asm volatile("s_waitcnt vmcnt(0)" ::: "memory");
    else if constexpr (N == 2) asm volatile("s_waitcnt vmcnt(2)" ::: "memory");
    else if constexpr (N == 3) asm volatile("s_waitcnt vmcnt(3)" ::: "memory");
    else if constexpr (N == 4) asm volatile("s_waitcnt vmcnt(4)" ::: "memory");
    else if constexpr (N == 8) asm volatile("s_waitcnt vmcnt(8)" ::: "memory");
}

// ---------------------------------------------------------------------------
// fp32 -> bf16 conversion of z, wq, wk, wv, wo (one kernel, 8 elems/thread)
// ---------------------------------------------------------------------------
__global__ __launch_bounds__(256) void convert_all(
    const float* __restrict__ z, const float* __restrict__ wq,
    const float* __restrict__ wk, const float* __restrict__ wv,
    const float* __restrict__ wo,
    u16* __restrict__ zb, u16* __restrict__ wqb, u16* __restrict__ wkb,
    u16* __restrict__ wvb, u16* __restrict__ wob)
{
    int g = blockIdx.x * 256 + threadIdx.x;      // group of 8 elements
    const float* s; u16* d;
    if (g < 786432)       { s = z;  d = zb;  }
    else if (g < 860160)  { s = wq; d = wqb; g -= 786432; }
    else if (g < 933888)  { s = wk; d = wkb; g -= 860160; }
    else if (g < 1007616) { s = wv; d = wvb; g -= 933888; }
    else                  { s = wo; d = wob; g -= 1007616; }
    float4 a = *(const float4*)(s + (size_t)g * 8);
    float4 b = *(const float4*)(s + (size_t)g * 8 + 4);
    u16 t[8] = {f2bf(a.x), f2bf(a.y), f2bf(a.z), f2bf(a.w),
                f2bf(b.x), f2bf(b.y), f2bf(b.z), f2bf(b.w)};
    *(uint4*)(d + (size_t)g * 8) = *(const uint4*)t;
}

// ---------------------------------------------------------------------------
// r9-proven dbuf glds K-loop (one __syncthreads/iter) for oproj (256 thr).
// LDS 16B cells: cell(row,kq) = row*4 + (kq ^ ((row>>1)&3)).
// ---------------------------------------------------------------------------
template <int MI>
__device__ __forceinline__ void gemm_mainloop(
    const u16* __restrict__ A, const u16* __restrict__ B,
    u16* As, u16* Bs, f32x4 (&acc)[MI][4], int m0, int lda, int ldb, int K)
{
    const int t = threadIdx.x;
    const int w = t >> 6, lane = t & 63, quad = lane >> 4, lc = lane & 15;
    const int wm = w >> 1, wn = w & 1;
    const int swz = (lc >> 1) & 3;
    constexpr int NA = MI / 2;
    constexpr int ASZ = 1024 * MI;

    const u16* pa[NA]; int la[NA];
    #pragma unroll
    for (int j = 0; j < NA; j++) {
        const int c = j * 256 + t;
        const int row = c >> 2;
        const int kq = (c & 3) ^ ((row >> 1) & 3);
        pa[j] = &A[(size_t)(m0 + row) * lda + kq * 8];
        la[j] = (j * 256 + w * 64) * 8;
    }
    const u16* pb[2]; int lb[2];
    #pragma unroll
    for (int j = 0; j < 2; j++) {
        const int c = j * 256 + t;
        const int row = c >> 2;
        const int kq = (c & 3) ^ ((row >> 1) & 3);
        pb[j] = &B[(size_t)row * ldb + kq * 8];
        lb[j] = (j * 256 + w * 64) * 8;
    }

    #pragma unroll
    for (int j = 0; j < NA; j++) glds16(pa[j], As + la[j]);
    #pragma unroll
    for (int j = 0; j < 2; j++) glds16(pb[j], Bs + lb[j]);
    __syncthreads();

    int buf = 0;
    for (int k0 = 0; k0 < K; k0 += 32) {
        if (k0 + 32 < K) {
            const int na = (buf ^ 1) * ASZ, nbb = (buf ^ 1) * 4096;
            #pragma unroll
            for (int j = 0; j < NA; j++) glds16(pa[j] + k0 + 32, As + na + la[j]);
            #pragma unroll
            for (int j = 0; j < 2; j++)  glds16(pb[j] + k0 + 32, Bs + nbb + lb[j]);
        }
        bf16x8 af[MI], bfr[4];
        #pragma unroll
        for (int i = 0; i < MI; i++) {
            const int row = 32 * NA * wm + 16 * i + lc;
            af[i] = *(const bf16x8*)&As[buf * ASZ + (row * 4 + (quad ^ swz)) * 8];
        }
        #pragma unroll
        for (int j = 0; j < 4; j++) {
            const int row = 64 * wn + 16 * j + lc;
            bfr[j] = *(const bf16x8*)&Bs[buf * 4096 + (row * 4 + (quad ^ swz)) * 8];
        }
        #pragma unroll
        for (int i = 0; i < MI; i++)
            #pragma unroll
            for (int j = 0; j < 4; j++)
                acc[i][j] = __builtin_amdgcn_mfma_f32_16x16x32_bf16(af[i], bfr[j], acc[i][j], 0, 0, 0);
        __syncthreads();
        buf ^= 1;
    }
}

// ---------------------------------------------------------------------------
// QKV: 256 threads (4 waves 2x2), tile 128x128, BK 32, manual 2-bar pipeline
// (r0-proven, best measured 51.0us), glds-only staging, XCD-aware 1-D grid
// (1152): n = d/64, m = d%64 -> XCD = m%8. LDS 32 KB dbuf.
// ---------------------------------------------------------------------------
__global__ __launch_bounds__(256) void qkv_gemm(
    const u16* __restrict__ zb, const u16* __restrict__ wqb,
    const u16* __restrict__ wkb, const u16* __restrict__ wvb,
    u16* __restrict__ qkb, u16* __restrict__ vt)
{
    __shared__ __align__(16) u16 As[8192], Bs[8192];   // dbuf: 4096 u16 per buffer
    const int d = blockIdx.x;
    const int n0 = (d >> 6) * 128, m0 = (d & 63) * 128;
    const u16* Bp;
    if (n0 < 768)       Bp = wqb + (size_t)n0 * 768;
    else if (n0 < 1536) Bp = wkb + (size_t)(n0 - 768) * 768;
    else                Bp = wvb + (size_t)(n0 - 1536) * 768;

    const int t = threadIdx.x;
    const int w = t >> 6, lane = t & 63, quad = lane >> 4, lc = lane & 15;
    const int wm = w >> 1, wn = w & 1;
    const int swz = (lc >> 1) & 3;

    const u16* pa[2]; const u16* pb[2]; int la[2], lb[2];
    #pragma unroll
    for (int j = 0; j < 2; j++) {
        const int c = j * 256 + t;
        const int row = c >> 2;
        const int kq = (c & 3) ^ ((row >> 1) & 3);
        pa[j] = &zb[(size_t)(m0 + row) * 768 + kq * 8];
        pb[j] = &Bp[(size_t)row * 768 + kq * 8];
        la[j] = lb[j] = (j * 256 + w * 64) * 8;    // wave-uniform cell base * 8
    }

    // prologue: tile0 -> buf0, tile1 -> buf1 (4 glds per thread per tile)
    glds16(pa[0], As + la[0]);  glds16(pa[1], As + la[1]);
    glds16(pb[0], Bs + lb[0]);  glds16(pb[1], Bs + lb[1]);
    glds16(pa[0] + 32, As + 4096 + la[0]);  glds16(pa[1] + 32, As + 4096 + la[1]);
    glds16(pb[0] + 32, Bs + 4096 + lb[0]);  glds16(pb[1] + 32, Bs + 4096 + lb[1]);

    f32x4 acc[4][4] = {};
    int buf = 0;
    for (int bk = 0; bk < 24; bk++) {
        if (bk + 1 < 24) waitv<4>(); else waitv<0>();   // tile bk landed
        bar();
        bf16x8 af[4], bfr[4];
        #pragma unroll
        for (int i = 0; i < 4; i++) {
            const int row = 64 * wm + 16 * i + lc;
            af[i] = *(const bf16x8*)&As[buf * 4096 + (row * 4 + (quad ^ swz)) * 8];
        }
        #pragma unroll
        for (int j = 0; j < 4; j++) {
            const int row = 64 * wn + 16 * j + lc;
            bfr[j] = *(const bf16x8*)&Bs[buf * 4096 + (row * 4 + (quad ^ swz)) * 8];
        }
        #pragma unroll
        for (int i = 0; i < 4; i++)
            #pragma unroll
            for (int j = 0; j < 4; j++)
                acc[i][j] = __builtin_amdgcn_mfma_f32_16x16x32_bf16(af[i], bfr[j], acc[i][j], 0, 0, 0);
        bar();                          // all waves' frag reads done
        if (bk + 2 < 24) {              // tile bk+2 -> the buffer just read
            const int k2 = (bk + 2) * 32;
            glds16(pa[0] + k2, As + buf * 4096 + la[0]);
            glds16(pa[1] + k2, As + buf * 4096 + la[1]);
            glds16(pb[0] + k2, Bs + buf * 4096 + lb[0]);
            glds16(pb[1] + k2, Bs + buf * 4096 + lb[1]);
        }
        buf ^= 1;
    }

    if (n0 < 1536) {
        #pragma unroll
        for (int i = 0; i < 4; i++)
            #pragma unroll
            for (int j = 0; j < 4; j++) {
                const int col = n0 + 64 * wn + 16 * j + lc;
                #pragma unroll
                for (int r = 0; r < 4; r++) {
                    const int row = m0 + 64 * wm + 16 * i + quad * 4 + r;
                    qkb[(size_t)row * 1536 + col] = f2bf_fast(acc[i][j][r]);
                }
            }
    } else {
        #pragma unroll
        for (int i = 0; i < 4; i++)
            #pragma unroll
            for (int j = 0; j < 4; j++) {
                const int c = (n0 - 1536) + 64 * wn + 16 * j + lc;   // 0..767
                const int h = c >> 6, dd = c & 63;
                const int tok0 = m0 + 64 * wm + 16 * i + quad * 4;
                const int b = tok0 >> 10, n = tok0 & 1023;
                ushort4 pk = { f2bf_fast(acc[i][j][0]), f2bf_fast(acc[i][j][1]),
                               f2bf_fast(acc[i][j][2]), f2bf_fast(acc[i][j][3]) };
                *(ushort4*)&vt[(((size_t)(b * 12 + h)) * 64 + dd) * 1024 + n] = pk;
            }
    }
}

// out[8192,768](f32) = obuf[8192,768](bf16) x wob[768,768]^T + bo
// M-tile 64 (MI=2). XCD-aware 1-D grid (768): n = d/128, m = d%128.
__global__ __launch_bounds__(256) void oproj_gemm(
    const u16* __restrict__ ob, const u16* __restrict__ wob,
    const float* __restrict__ bo, float* __restrict__ out)
{
    __shared__ __align__(16) u16 As[4096], Bs[8192];
    const int d = blockIdx.x;
    const int n0 = (d >> 7) * 128, m0 = (d & 127) * 64;
    f32x4 acc[2][4] = {};
    gemm_mainloop<2>(ob, wob + (size_t)n0 * 768, As, Bs, acc, m0, 768, 768, 768);

    const int t = threadIdx.x;
    const int w = t >> 6, lane = t & 63, quad = lane >> 4, lc = lane & 15;
    const int wm = w >> 1, wn = w & 1;
    #pragma unroll
    for (int i = 0; i < 2; i++)
        #pragma unroll
        for (int j = 0; j < 4; j++) {
            const int col = n0 + 64 * wn + 16 * j + lc;
            const float bv = bo[col];
            #pragma unroll
            for (int r = 0; r < 4; r++) {
                const int row = m0 + 32 * wm + 16 * i + quad * 4 + r;
                out[(size_t)row * 768 + col] = acc[i][j][r] + bv;
            }
        }
}

// ---------------------------------------------------------------------------
// Flash attention r7: KVBLK=64, K double-buffered + prefetched one iteration
// ahead (K(kt+1) issued at top of iter kt, consumed next iter -> full-iter
// latency cover; the r6-exposed per-iter K stall removed). 256 thr = 4 waves;
// wave owns 32 q-rows as 2 row-groups (r6 dedup kept). P pad removed: XOR
// slot-swizzle slot^=(row>>1)&7 (reads 2-way/free, writes spread).
// LDS 40 KB (K 2x8 + V 8 + P 16) -> 4 blocks/CU, 16 waves/CU (was 12).
// vmcnt ledger: steady 6 outstanding; waitv<4> drains K(kt), waitv<2> V(kt).
// ---------------------------------------------------------------------------
__global__ __launch_bounds__(256, 4) void attn_kernel(
    const u16* __restrict__ qkb, const u16* __restrict__ vt,
    u16* __restrict__ obuf)
{
    const int b = blockIdx.x / 12, h = blockIdx.x % 12;
    const int q0 = blockIdx.y * 128;
    const int t = threadIdx.x;
    const int w = t >> 6, lane = t & 63, quad = lane >> 4, lc = lane & 15;

    const u16* Qp  = qkb + (size_t)b * 1024 * 1536 + h * 64;
    const u16* Kp  = Qp + 768;
    const u16* Vtp = vt + ((size_t)(b * 12 + h)) * 64 * 1024;

    __shared__ __align__(16) u16 Ks[2][4096];   // K dbuf: 64 rows x 8 slots x 8 u16
    __shared__ __align__(16) u16 Vts[4096];     // V^T: 64 d x 8 slots x 8 u16
    __shared__ __align__(16) u16 Ps[8192];      // P: 128 q x 8 slots x 8 u16, XOR swz

    // K staging: 512 cells, c = j*256 + t (2 cells/thread)
    const u16* kp[2]; int kl[2];
    #pragma unroll
    for (int j = 0; j < 2; j++) {
        const int c = j * 256 + t;
        const int row = c >> 3;                    // 0..63
        const int kq = (c & 7) ^ ((row >> 1) & 7);
        kp[j] = Kp + (size_t)row * 1536 + kq * 8;
        kl[j] = (j * 256 + w * 64) * 8;            // wave-uniform cell base * 8
    }
    // V staging: 512 cells, c = s*64 + lane, s = 2w+s2 (2 cells/thread)
    const u16* vp[2]; u16* vl[2];
    #pragma unroll
    for (int s2 = 0; s2 < 2; s2++) {
        const int s = 2 * w + s2;
        const int c = s * 64 + lane;
        const int dd = c >> 3, kq = (c & 7) ^ (dd & 7);
        vp[s2] = Vtp + (size_t)dd * 1024 + kq * 8;
        vl[s2] = &Vts[s * 512];
    }

    // Q fragments (A-layout m=lc): this wave's 32 q rows, two row-groups
    bf16x8 qf[2][2];
    #pragma unroll
    for (int rg = 0; rg < 2; rg++)
        #pragma unroll
        for (int kk = 0; kk < 2; kk++)
            qf[rg][kk] = *(const bf16x8*)&Qp[(size_t)(q0 + 32 * w + 16 * rg + lc) * 1536
                                             + kk * 32 + quad * 8];

    f32x4 oacc[2][4] = {};
    float lsum[2][4] = {};                  // lane-partial row sums per row-group

    const float cs = 0.18033688011112042f;  // log2(e) / sqrt(64)
    const int swk = (lc >> 1) & 7;
    const int pR0 = 32 * w;                 // wave's P row base

    waitv<0>();                             // qf drained; clean vmcnt at loop entry
    // prologue: K(0) -> Ks[0]
    glds16(kp[0], &Ks[0][0] + kl[0]);
    glds16(kp[1], &Ks[0][0] + kl[1]);

    for (int kt = 0; kt < 16; kt++) {
        const int kb = kt * 64;
        bar();                              // prior iter's LDS reads done
        glds16(vp[0] + kb, vl[0]);          // V(kt) (2 glds)
        glds16(vp[1] + kb, vl[1]);
        if (kt + 1 < 16) {                  // prefetch K(kt+1) -> other buffer
            const size_t kb1 = (size_t)(kt + 1) * 64 * 1536;
            u16* kd = &Ks[(kt + 1) & 1][0];
            glds16(kp[0] + kb1, kd + kl[0]);
            glds16(kp[1] + kb1, kd + kl[1]);
            waitv<4>();                     // K(kt) landed (V + K(kt+1) in flight)
        } else {
            waitv<2>();                     // K(15) landed (V in flight)
        }
        bar();                              // K visible to all waves

        // S = Q K^T over 64 kv rows
        const u16* Kc = &Ks[kt & 1][0];
        f32x4 sacc[2][4] = {};
        #pragma unroll
        for (int j = 0; j < 4; j++) {
            const int nrow = 16 * j + lc;
            bf16x8 kf0 = *(const bf16x8*)&Kc[(nrow * 8 + (quad ^ swk)) * 8];
            bf16x8 kf1 = *(const bf16x8*)&Kc[(nrow * 8 + ((4 + quad) ^ swk)) * 8];
            #pragma unroll
            for (int rg = 0; rg < 2; rg++) {
                sacc[rg][j] = __builtin_amdgcn_mfma_f32_16x16x32_bf16(qf[rg][0], kf0, sacc[rg][j], 0, 0, 0);
                sacc[rg][j] = __builtin_amdgcn_mfma_f32_16x16x32_bf16(qf[rg][1], kf1, sacc[rg][j], 0, 0, 0);
            }
        }
        if (kt + 1 < 16) waitv<2>();        // V(kt) landed (K(kt+1) stays in flight)
        else             waitv<0>();
        bar();                              // V visible; P region safe to rewrite

        // P = exp2(S*cs); lane-partial l; write P bf16 (XOR slot swizzle)
        #pragma unroll
        for (int rg = 0; rg < 2; rg++) {
            const int Rb = pR0 + 16 * rg + quad * 4;
            #pragma unroll
            for (int j = 0; j < 4; j++)
                #pragma unroll
                for (int r = 0; r < 4; r++) {
                    float p = __builtin_amdgcn_exp2f(sacc[rg][j][r] * cs);
                    lsum[rg][r] += p;
                    const int R = Rb + r;
                    const int slot = (2 * j + (lc >> 3)) ^ ((R >> 1) & 7);
                    Ps[R * 64 + slot * 8 + (lc & 7)] = f2bf_fast(p);
                }
        }

        // O += P V : A = own 32 P-rows (same-wave DS order), kv = 64 (ks 0..1)
        #pragma unroll
        for (int ks = 0; ks < 2; ks++) {
            bf16x8 pa[2];
            #pragma unroll
            for (int rg = 0; rg < 2; rg++) {
                const int Rp = pR0 + 16 * rg + lc;
                pa[rg] = *(const bf16x8*)&Ps[Rp * 64 + (((ks * 4 + quad) ^ ((Rp >> 1) & 7)) << 3)];
            }
            #pragma unroll
            for (int jd = 0; jd < 4; jd++) {
                const int dd = 16 * jd + lc;
                bf16x8 vb = *(const bf16x8*)&Vts[(dd * 8 + ((ks * 4 + quad) ^ (dd & 7))) * 8];
                #pragma unroll
                for (int rg = 0; rg < 2; rg++)
                    oacc[rg][jd] = __builtin_amdgcn_mfma_f32_16x16x32_bf16(pa[rg], vb, oacc[rg][jd], 0, 0, 0);
            }
        }
    }

    // one shuffle-reduce of l across the 16 lanes holding each row
    #pragma unroll
    for (int off = 1; off < 16; off <<= 1)
        #pragma unroll
        for (int rg = 0; rg < 2; rg++)
            #pragma unroll
            for (int r = 0; r < 4; r++)
                lsum[rg][r] += __shfl_xor(lsum[rg][r], off, 64);

    // epilogue: O * (1/l), store bf16 into [B,N,H*Dh]
    float invl[2][4];
    #pragma unroll
    for (int rg = 0; rg < 2; rg++)
        #pragma unroll
        for (int r = 0; r < 4; r++) invl[rg][r] = __builtin_amdgcn_rcpf(lsum[rg][r]);
    #pragma unroll
    for (int rg = 0; rg < 2; rg++)
        #pragma unroll
        for (int jd = 0; jd < 4; jd++)
            #pragma unroll
            for (int r = 0; r < 4; r++) {
                const int row = q0 + 32 * w + 16 * rg + quad * 4 + r;
                const int col = h * 64 + 16 * jd + lc;
                obuf[((size_t)b * 1024 + row) * 768 + col] = f2bf_fast(oacc[rg][jd][r] * invl[rg][r]);
            }
}

extern "C" void kernel_launch(void* const* d_in, const int* in_sizes, int n_in,
                              void* d_out, int out_size, void* d_ws, size_t ws_size,
                              hipStream_t stream) {
    const float* z  = (const float*)d_in[0];
    const float* wq = (const float*)d_in[1];
    const float* wk = (const float*)d_in[2];
    const float* wv = (const float*)d_in[3];
    const float* wo = (const float*)d_in[4];
    const float* bo = (const float*)d_in[5];

    u16* ws16 = (u16*)d_ws;
    u16* zb   = ws16;                 // 6,291,456 u16 (reused as obuf)
    u16* wqb  = zb  + 6291456;        //   589,824 each
    u16* wkb  = wqb + 589824;
    u16* wvb  = wkb + 589824;
    u16* wob  = wvb + 589824;
    u16* vt   = wob + 589824;         // 6,291,456   (total 29.9 MB)
    u16* qkb  = (u16*)d_out;          // 12,582,912 u16 == d_out bytes; dead before oproj
    u16* obuf = zb;                   // zb dead after qkv_gemm
    float* out = (float*)d_out;

    convert_all<<<4224, 256, 0, stream>>>(z, wq, wk, wv, wo, zb, wqb, wkb, wvb, wob);
    qkv_gemm<<<1152, 256, 0, stream>>>(zb, wqb, wkb, wvb, qkb, vt);
    attn_kernel<<<dim3(96, 8), 256, 0, stream>>>(qkb, vt, obuf);
    oproj_gemm<<<768, 256, 0, stream>>>(obuf, wob, bo, out);
}

// Round 14
// 191.632 us; speedup vs baseline: 1.0279x; 1.0279x over previous
//
#include <hip/hip_runtime.h>
#include <hip/hip_bf16.h>
#include <stdint.h>

typedef unsigned short u16;
typedef __attribute__((ext_vector_type(8))) short bf16x8;   // 8 bf16 in 4 VGPRs
typedef __attribute__((ext_vector_type(4))) float f32x4;

__device__ __forceinline__ u16 f2bf(float f) {
    union { float f; unsigned int i; } c; c.f = f;
    unsigned int x = c.i;
    return (u16)((x + 0x7FFFu + ((x >> 16) & 1u)) >> 16);   // RNE
}
__device__ __forceinline__ u16 f2bf_fast(float f) {         // tie-away, 2 VALU
    union { float f; unsigned int i; } c; c.f = f;
    return (u16)((c.i + 0x8000u) >> 16);
}

// async global->LDS, 16B per lane; LDS dst = uniform base + lane*16
__device__ __forceinline__ void glds16(const u16* g, u16* l) {
    __builtin_amdgcn_global_load_lds(
        (const __attribute__((address_space(1))) void*)g,
        (__attribute__((address_space(3))) void*)l, 16, 0, 0);
}

// manual sync: raw barrier + partial vmcnt waits. LESSON (r13/r14): only
// glds staging (vmcnt-tracked) may publish LDS across waves with these;
// cross-wave ds_write publication raced even with lgkmcnt(0) — banned.
__device__ __forceinline__ void bar() { asm volatile("s_barrier" ::: "memory"); }
template <int N> __device__ __forceinline__ void waitv() {
    if constexpr (N == 0)      asm volatile("s_waitcnt vmcnt(0)" ::: "memory");
    else if constexpr (N == 2) asm volatile("s_waitcnt vmcnt(2)" ::: "memory");
    else if constexpr (N == 3) asm volatile("s_waitcnt vmcnt(3)" ::: "memory");
    else if constexpr (N == 4) asm volatile("s_waitcnt vmcnt(4)" ::: "memory");
    else if constexpr (N == 8) asm volatile("s_waitcnt vmcnt(8)" ::: "memory");
}

// ---------------------------------------------------------------------------
// fp32 -> bf16 conversion of z, wq, wk, wv, wo (one kernel, 8 elems/thread)
// ---------------------------------------------------------------------------
__global__ __launch_bounds__(256) void convert_all(
    const float* __restrict__ z, const float* __restrict__ wq,
    const float* __restrict__ wk, const float* __restrict__ wv,
    const float* __restrict__ wo,
    u16* __restrict__ zb, u16* __restrict__ wqb, u16* __restrict__ wkb,
    u16* __restrict__ wvb, u16* __restrict__ wob)
{
    int g = blockIdx.x * 256 + threadIdx.x;      // group of 8 elements
    const float* s; u16* d;
    if (g < 786432)       { s = z;  d = zb;  }
    else if (g < 860160)  { s = wq; d = wqb; g -= 786432; }
    else if (g < 933888)  { s = wk; d = wkb; g -= 860160; }
    else if (g < 1007616) { s = wv; d = wvb; g -= 933888; }
    else                  { s = wo; d = wob; g -= 1007616; }
    float4 a = *(const float4*)(s + (size_t)g * 8);
    float4 b = *(const float4*)(s + (size_t)g * 8 + 4);
    u16 t[8] = {f2bf(a.x), f2bf(a.y), f2bf(a.z), f2bf(a.w),
                f2bf(b.x), f2bf(b.y), f2bf(b.z), f2bf(b.w)};
    *(uint4*)(d + (size_t)g * 8) = *(const uint4*)t;
}

// ---------------------------------------------------------------------------
// QKV: 256 threads (4 waves 2x2), tile 128x128, BK 32, manual 2-bar pipeline
// (r0-proven, best measured 51.0us), glds-only staging, XCD-aware 1-D grid
// (1152): n = d/64, m = d%64 -> XCD = m%8. LDS 32 KB dbuf.
// ---------------------------------------------------------------------------
__global__ __launch_bounds__(256) void qkv_gemm(
    const u16* __restrict__ zb, const u16* __restrict__ wqb,
    const u16* __restrict__ wkb, const u16* __restrict__ wvb,
    u16* __restrict__ qkb, u16* __restrict__ vt)
{
    __shared__ __align__(16) u16 As[8192], Bs[8192];   // dbuf: 4096 u16 per buffer
    const int d = blockIdx.x;
    const int n0 = (d >> 6) * 128, m0 = (d & 63) * 128;
    const u16* Bp;
    if (n0 < 768)       Bp = wqb + (size_t)n0 * 768;
    else if (n0 < 1536) Bp = wkb + (size_t)(n0 - 768) * 768;
    else                Bp = wvb + (size_t)(n0 - 1536) * 768;

    const int t = threadIdx.x;
    const int w = t >> 6, lane = t & 63, quad = lane >> 4, lc = lane & 15;
    const int wm = w >> 1, wn = w & 1;
    const int swz = (lc >> 1) & 3;

    const u16* pa[2]; const u16* pb[2]; int la[2], lb[2];
    #pragma unroll
    for (int j = 0; j < 2; j++) {
        const int c = j * 256 + t;
        const int row = c >> 2;
        const int kq = (c & 3) ^ ((row >> 1) & 3);
        pa[j] = &zb[(size_t)(m0 + row) * 768 + kq * 8];
        pb[j] = &Bp[(size_t)row * 768 + kq * 8];
        la[j] = lb[j] = (j * 256 + w * 64) * 8;    // wave-uniform cell base * 8
    }

    // prologue: tile0 -> buf0, tile1 -> buf1 (4 glds per thread per tile)
    glds16(pa[0], As + la[0]);  glds16(pa[1], As + la[1]);
    glds16(pb[0], Bs + lb[0]);  glds16(pb[1], Bs + lb[1]);
    glds16(pa[0] + 32, As + 4096 + la[0]);  glds16(pa[1] + 32, As + 4096 + la[1]);
    glds16(pb[0] + 32, Bs + 4096 + lb[0]);  glds16(pb[1] + 32, Bs + 4096 + lb[1]);

    f32x4 acc[4][4] = {};
    int buf = 0;
    for (int bk = 0; bk < 24; bk++) {
        if (bk + 1 < 24) waitv<4>(); else waitv<0>();   // tile bk landed
        bar();
        bf16x8 af[4], bfr[4];
        #pragma unroll
        for (int i = 0; i < 4; i++) {
            const int row = 64 * wm + 16 * i + lc;
            af[i] = *(const bf16x8*)&As[buf * 4096 + (row * 4 + (quad ^ swz)) * 8];
        }
        #pragma unroll
        for (int j = 0; j < 4; j++) {
            const int row = 64 * wn + 16 * j + lc;
            bfr[j] = *(const bf16x8*)&Bs[buf * 4096 + (row * 4 + (quad ^ swz)) * 8];
        }
        #pragma unroll
        for (int i = 0; i < 4; i++)
            #pragma unroll
            for (int j = 0; j < 4; j++)
                acc[i][j] = __builtin_amdgcn_mfma_f32_16x16x32_bf16(af[i], bfr[j], acc[i][j], 0, 0, 0);
        bar();                          // all waves' frag reads done
        if (bk + 2 < 24) {              // tile bk+2 -> the buffer just read
            const int k2 = (bk + 2) * 32;
            glds16(pa[0] + k2, As + buf * 4096 + la[0]);
            glds16(pa[1] + k2, As + buf * 4096 + la[1]);
            glds16(pb[0] + k2, Bs + buf * 4096 + lb[0]);
            glds16(pb[1] + k2, Bs + buf * 4096 + lb[1]);
        }
        buf ^= 1;
    }

    if (n0 < 1536) {
        #pragma unroll
        for (int i = 0; i < 4; i++)
            #pragma unroll
            for (int j = 0; j < 4; j++) {
                const int col = n0 + 64 * wn + 16 * j + lc;
                #pragma unroll
                for (int r = 0; r < 4; r++) {
                    const int row = m0 + 64 * wm + 16 * i + quad * 4 + r;
                    qkb[(size_t)row * 1536 + col] = f2bf_fast(acc[i][j][r]);
                }
            }
    } else {
        #pragma unroll
        for (int i = 0; i < 4; i++)
            #pragma unroll
            for (int j = 0; j < 4; j++) {
                const int c = (n0 - 1536) + 64 * wn + 16 * j + lc;   // 0..767
                const int h = c >> 6, dd = c & 63;
                const int tok0 = m0 + 64 * wm + 16 * i + quad * 4;
                const int b = tok0 >> 10, n = tok0 & 1023;
                ushort4 pk = { f2bf_fast(acc[i][j][0]), f2bf_fast(acc[i][j][1]),
                               f2bf_fast(acc[i][j][2]), f2bf_fast(acc[i][j][3]) };
                *(ushort4*)&vt[(((size_t)(b * 12 + h)) * 64 + dd) * 1024 + n] = pk;
            }
    }
}

// ---------------------------------------------------------------------------
// oproj r12: out[8192,768](f32) = obuf[8192,768](bf16) x wob[768,768]^T + bo.
// Ported to the qkv-proven 2-bar manual pipeline (was __syncthreads-drain
// mainloop = full vmcnt(0) drain of same-iteration prefetch each K-step).
// M-tile 64 (MI=2), N-tile 128, BK 32; 3 glds/thread/tile (1 A + 2 B);
// steady 6 outstanding, waitv<3> drains exactly the oldest tile.
// XCD-aware 1-D grid (768): n = d/128, m = d%128. LDS 24 KB dbuf.
// ---------------------------------------------------------------------------
__global__ __launch_bounds__(256) void oproj_gemm(
    const u16* __restrict__ ob, const u16* __restrict__ wob,
    const float* __restrict__ bo, float* __restrict__ out)
{
    __shared__ __align__(16) u16 As[4096], Bs[8192];   // dbuf: A 2x2048, B 2x4096
    const int d = blockIdx.x;
    const int n0 = (d >> 7) * 128, m0 = (d & 127) * 64;

    const int t = threadIdx.x;
    const int w = t >> 6, lane = t & 63, quad = lane >> 4, lc = lane & 15;
    const int wm = w >> 1, wn = w & 1;
    const int swz = (lc >> 1) & 3;

    // A staging: 256 cells (64 rows x 4 kq), 1 cell/thread
    const int arow = t >> 2;
    const int akq = (t & 3) ^ ((arow >> 1) & 3);
    const u16* pa = &ob[(size_t)(m0 + arow) * 768 + akq * 8];
    const int la = (w * 64) * 8;                   // wave-uniform cell base * 8
    // B staging: 512 cells, 2 cells/thread
    const u16* pb[2]; int lb[2];
    #pragma unroll
    for (int j = 0; j < 2; j++) {
        const int c = j * 256 + t;
        const int row = c >> 2;
        const int kq = (c & 3) ^ ((row >> 1) & 3);
        pb[j] = &wob[(size_t)(n0 + row) * 768 + kq * 8];
        lb[j] = (j * 256 + w * 64) * 8;
    }

    // prologue: tile0 -> buf0, tile1 -> buf1 (3 glds per thread per tile)
    glds16(pa, As + la);
    glds16(pb[0], Bs + lb[0]);  glds16(pb[1], Bs + lb[1]);
    glds16(pa + 32, As + 2048 + la);
    glds16(pb[0] + 32, Bs + 4096 + lb[0]);  glds16(pb[1] + 32, Bs + 4096 + lb[1]);

    f32x4 acc[2][4] = {};
    int buf = 0;
    for (int bk = 0; bk < 24; bk++) {
        if (bk + 1 < 24) waitv<3>(); else waitv<0>();   // tile bk landed
        bar();
        bf16x8 af[2], bfr[4];
        #pragma unroll
        for (int i = 0; i < 2; i++) {
            const int row = 32 * wm + 16 * i + lc;
            af[i] = *(const bf16x8*)&As[buf * 2048 + (row * 4 + (quad ^ swz)) * 8];
        }
        #pragma unroll
        for (int j = 0; j < 4; j++) {
            const int row = 64 * wn + 16 * j + lc;
            bfr[j] = *(const bf16x8*)&Bs[buf * 4096 + (row * 4 + (quad ^ swz)) * 8];
        }
        #pragma unroll
        for (int i = 0; i < 2; i++)
            #pragma unroll
            for (int j = 0; j < 4; j++)
                acc[i][j] = __builtin_amdgcn_mfma_f32_16x16x32_bf16(af[i], bfr[j], acc[i][j], 0, 0, 0);
        bar();                          // all waves' frag reads done
        if (bk + 2 < 24) {              // tile bk+2 -> the buffer just read
            const int k2 = (bk + 2) * 32;
            glds16(pa + k2, As + buf * 2048 + la);
            glds16(pb[0] + k2, Bs + buf * 4096 + lb[0]);
            glds16(pb[1] + k2, Bs + buf * 4096 + lb[1]);
        }
        buf ^= 1;
    }

    #pragma unroll
    for (int i = 0; i < 2; i++)
        #pragma unroll
        for (int j = 0; j < 4; j++) {
            const int col = n0 + 64 * wn + 16 * j + lc;
            const float bv = bo[col];
            #pragma unroll
            for (int r = 0; r < 4; r++) {
                const int row = m0 + 32 * wm + 16 * i + quad * 4 + r;
                out[(size_t)row * 768 + col] = acc[i][j][r] + bv;
            }
        }
}

// ---------------------------------------------------------------------------
// Flash attention r7 (r12-measured, passed): KVBLK=64, K double-buffered +
// prefetched one iteration ahead. 256 thr = 4 waves; wave owns 32 q-rows as
// 2 row-groups. P XOR slot-swizzle. LDS 40 KB -> 4 blocks/CU.
// vmcnt ledger: steady 6 outstanding; waitv<4> drains K(kt), waitv<2> V(kt).
// ---------------------------------------------------------------------------
__global__ __launch_bounds__(256, 4) void attn_kernel(
    const u16* __restrict__ qkb, const u16* __restrict__ vt,
    u16* __restrict__ obuf)
{
    const int b = blockIdx.x / 12, h = blockIdx.x % 12;
    const int q0 = blockIdx.y * 128;
    const int t = threadIdx.x;
    const int w = t >> 6, lane = t & 63, quad = lane >> 4, lc = lane & 15;

    const u16* Qp  = qkb + (size_t)b * 1024 * 1536 + h * 64;
    const u16* Kp  = Qp + 768;
    const u16* Vtp = vt + ((size_t)(b * 12 + h)) * 64 * 1024;

    __shared__ __align__(16) u16 Ks[2][4096];   // K dbuf: 64 rows x 8 slots x 8 u16
    __shared__ __align__(16) u16 Vts[4096];     // V^T: 64 d x 8 slots x 8 u16
    __shared__ __align__(16) u16 Ps[8192];      // P: 128 q x 8 slots x 8 u16, XOR swz

    // K staging: 512 cells, c = j*256 + t (2 cells/thread)
    const u16* kp[2]; int kl[2];
    #pragma unroll
    for (int j = 0; j < 2; j++) {
        const int c = j * 256 + t;
        const int row = c >> 3;                    // 0..63
        const int kq = (c & 7) ^ ((row >> 1) & 7);
        kp[j] = Kp + (size_t)row * 1536 + kq * 8;
        kl[j] = (j * 256 + w * 64) * 8;            // wave-uniform cell base * 8
    }
    // V staging: 512 cells, c = s*64 + lane, s = 2w+s2 (2 cells/thread)
    const u16* vp[2]; u16* vl[2];
    #pragma unroll
    for (int s2 = 0; s2 < 2; s2++) {
        const int s = 2 * w + s2;
        const int c = s * 64 + lane;
        const int dd = c >> 3, kq = (c & 7) ^ (dd & 7);
        vp[s2] = Vtp + (size_t)dd * 1024 + kq * 8;
        vl[s2] = &Vts[s * 512];
    }

    // Q fragments (A-layout m=lc): this wave's 32 q rows, two row-groups
    bf16x8 qf[2][2];
    #pragma unroll
    for (int rg = 0; rg < 2; rg++)
        #pragma unroll
        for (int kk = 0; kk < 2; kk++)
            qf[rg][kk] = *(const bf16x8*)&Qp[(size_t)(q0 + 32 * w + 16 * rg + lc) * 1536
                                             + kk * 32 + quad * 8];

    f32x4 oacc[2][4] = {};
    float lsum[2][4] = {};                  // lane-partial row sums per row-group

    const float cs = 0.18033688011112042f;  // log2(e) / sqrt(64)
    const int swk = (lc >> 1) & 7;
    const int pR0 = 32 * w;                 // wave's P row base

    waitv<0>();                             // qf drained; clean vmcnt at loop entry
    // prologue: K(0) -> Ks[0]
    glds16(kp[0], &Ks[0][0] + kl[0]);
    glds16(kp[1], &Ks[0][0] + kl[1]);

    for (int kt = 0; kt < 16; kt++) {
        const int kb = kt * 64;
        bar();                              // prior iter's LDS reads done
        glds16(vp[0] + kb, vl[0]);          // V(kt) (2 glds)
        glds16(vp[1] + kb, vl[1]);
        if (kt + 1 < 16) {                  // prefetch K(kt+1) -> other buffer
            const size_t kb1 = (size_t)(kt + 1) * 64 * 1536;
            u16* kd = &Ks[(kt + 1) & 1][0];
            glds16(kp[0] + kb1, kd + kl[0]);
            glds16(kp[1] + kb1, kd + kl[1]);
            waitv<4>();                     // K(kt) landed (V + K(kt+1) in flight)
        } else {
            waitv<2>();                     // K(15) landed (V in flight)
        }
        bar();                              // K visible to all waves

        // S = Q K^T over 64 kv rows
        const u16* Kc = &Ks[kt & 1][0];
        f32x4 sacc[2][4] = {};
        #pragma unroll
        for (int j = 0; j < 4; j++) {
            const int nrow = 16 * j + lc;
            bf16x8 kf0 = *(const bf16x8*)&Kc[(nrow * 8 + (quad ^ swk)) * 8];
            bf16x8 kf1 = *(const bf16x8*)&Kc[(nrow * 8 + ((4 + quad) ^ swk)) * 8];
            #pragma unroll
            for (int rg = 0; rg < 2; rg++) {
                sacc[rg][j] = __builtin_amdgcn_mfma_f32_16x16x32_bf16(qf[rg][0], kf0, sacc[rg][j], 0, 0, 0);
                sacc[rg][j] = __builtin_amdgcn_mfma_f32_16x16x32_bf16(qf[rg][1], kf1, sacc[rg][j], 0, 0, 0);
            }
        }
        if (kt + 1 < 16) waitv<2>();        // V(kt) landed (K(kt+1) stays in flight)
        else             waitv<0>();
        bar();                              // V visible; P region safe to rewrite

        // P = exp2(S*cs); lane-partial l; write P bf16 (XOR slot swizzle)
        #pragma unroll
        for (int rg = 0; rg < 2; rg++) {
            const int Rb = pR0 + 16 * rg + quad * 4;
            #pragma unroll
            for (int j = 0; j < 4; j++)
                #pragma unroll
                for (int r = 0; r < 4; r++) {
                    float p = __builtin_amdgcn_exp2f(sacc[rg][j][r] * cs);
                    lsum[rg][r] += p;
                    const int R = Rb + r;
                    const int slot = (2 * j + (lc >> 3)) ^ ((R >> 1) & 7);
                    Ps[R * 64 + slot * 8 + (lc & 7)] = f2bf_fast(p);
                }
        }

        // O += P V : A = own 32 P-rows (same-wave DS order), kv = 64 (ks 0..1)
        #pragma unroll
        for (int ks = 0; ks < 2; ks++) {
            bf16x8 pa[2];
            #pragma unroll
            for (int rg = 0; rg < 2; rg++) {
                const int Rp = pR0 + 16 * rg + lc;
                pa[rg] = *(const bf16x8*)&Ps[Rp * 64 + (((ks * 4 + quad) ^ ((Rp >> 1) & 7)) << 3)];
            }
            #pragma unroll
            for (int jd = 0; jd < 4; jd++) {
                const int dd = 16 * jd + lc;
                bf16x8 vb = *(const bf16x8*)&Vts[(dd * 8 + ((ks * 4 + quad) ^ (dd & 7))) * 8];
                #pragma unroll
                for (int rg = 0; rg < 2; rg++)
                    oacc[rg][jd] = __builtin_amdgcn_mfma_f32_16x16x32_bf16(pa[rg], vb, oacc[rg][jd], 0, 0, 0);
            }
        }
    }

    // one shuffle-reduce of l across the 16 lanes holding each row
    #pragma unroll
    for (int off = 1; off < 16; off <<= 1)
        #pragma unroll
        for (int rg = 0; rg < 2; rg++)
            #pragma unroll
            for (int r = 0; r < 4; r++)
                lsum[rg][r] += __shfl_xor(lsum[rg][r], off, 64);

    // epilogue: O * (1/l), store bf16 into [B,N,H*Dh]
    float invl[2][4];
    #pragma unroll
    for (int rg = 0; rg < 2; rg++)
        #pragma unroll
        for (int r = 0; r < 4; r++) invl[rg][r] = __builtin_amdgcn_rcpf(lsum[rg][r]);
    #pragma unroll
    for (int rg = 0; rg < 2; rg++)
        #pragma unroll
        for (int jd = 0; jd < 4; jd++)
            #pragma unroll
            for (int r = 0; r < 4; r++) {
                const int row = q0 + 32 * w + 16 * rg + quad * 4 + r;
                const int col = h * 64 + 16 * jd + lc;
                obuf[((size_t)b * 1024 + row) * 768 + col] = f2bf_fast(oacc[rg][jd][r] * invl[rg][r]);
            }
}

extern "C" void kernel_launch(void* const* d_in, const int* in_sizes, int n_in,
                              void* d_out, int out_size, void* d_ws, size_t ws_size,
                              hipStream_t stream) {
    const float* z  = (const float*)d_in[0];
    const float* wq = (const float*)d_in[1];
    const float* wk = (const float*)d_in[2];
    const float* wv = (const float*)d_in[3];
    const float* wo = (const float*)d_in[4];
    const float* bo = (const float*)d_in[5];

    u16* ws16 = (u16*)d_ws;
    u16* zb   = ws16;                 // 6,291,456 u16 (reused as obuf)
    u16* wqb  = zb  + 6291456;        //   589,824 each
    u16* wkb  = wqb + 589824;
    u16* wvb  = wkb + 589824;
    u16* wob  = wvb + 589824;
    u16* vt   = wob + 589824;         // 6,291,456   (total 29.9 MB)
    u16* qkb  = (u16*)d_out;          // 12,582,912 u16 == d_out bytes; dead before oproj
    u16* obuf = zb;                   // zb dead after qkv_gemm
    float* out = (float*)d_out;

    convert_all<<<4224, 256, 0, stream>>>(z, wq, wk, wv, wo, zb, wqb, wkb, wvb, wob);
    qkv_gemm<<<1152, 256, 0, stream>>>(zb, wqb, wkb, wvb, qkb, vt);
    attn_kernel<<<dim3(96, 8), 256, 0, stream>>>(qkb, vt, obuf);
    oproj_gemm<<<768, 256, 0, stream>>>(obuf, wob, bo, out);
}